// Round 1
// baseline (355.206 us; speedup 1.0000x reference)
//
#include <hip/hip_runtime.h>
#include <math.h>

#define NBLK 256

// ---------- preprocessing: CSR by dst ----------

__global__ __launch_bounds__(NBLK) void init_k(int* cnt, int* cursor, int n) {
    int i = blockIdx.x * blockDim.x + threadIdx.x;
    if (i < n) { cnt[i] = 0; cursor[i] = 0; }
}

__global__ __launch_bounds__(NBLK) void count_k(const int* __restrict__ dst, int E, int* __restrict__ cnt) {
    int e = blockIdx.x * blockDim.x + threadIdx.x;
    if (e < E) atomicAdd(&cnt[dst[e]], 1);
}

// chunk = 1024 elems per block (256 threads x 4)
__global__ __launch_bounds__(NBLK) void scan1_k(const int* __restrict__ cnt, int n,
                                                int* __restrict__ off, int* __restrict__ bsum) {
    __shared__ int ls[NBLK];
    int base = blockIdx.x * 1024 + threadIdx.x * 4;
    int v[4]; int s = 0;
#pragma unroll
    for (int i = 0; i < 4; ++i) {
        int idx = base + i;
        v[i] = (idx < n) ? cnt[idx] : 0;
        s += v[i];
    }
    ls[threadIdx.x] = s;
    __syncthreads();
    for (int o = 1; o < NBLK; o <<= 1) {
        int t = (threadIdx.x >= (unsigned)o) ? ls[threadIdx.x - o] : 0;
        __syncthreads();
        ls[threadIdx.x] += t;
        __syncthreads();
    }
    int excl = ls[threadIdx.x] - s;   // exclusive prefix of this thread within block
    int run = excl;
#pragma unroll
    for (int i = 0; i < 4; ++i) {
        int idx = base + i;
        if (idx < n) off[idx] = run;
        run += v[i];
    }
    if (threadIdx.x == NBLK - 1) bsum[blockIdx.x] = ls[NBLK - 1]; // block total
}

// nb <= 128 (N=100000 -> nb=98)
__global__ void scan2_k(int* bsum, int nb) {
    __shared__ int ls[128];
    int t = threadIdx.x;
    int v = (t < nb) ? bsum[t] : 0;
    ls[t] = v;
    __syncthreads();
    for (int o = 1; o < 128; o <<= 1) {
        int tv = (t >= o) ? ls[t - o] : 0;
        __syncthreads();
        ls[t] += tv;
        __syncthreads();
    }
    if (t < nb) bsum[t] = ls[t] - v;  // exclusive
}

__global__ __launch_bounds__(NBLK) void scan3_k(int* __restrict__ off, const int* __restrict__ bsum,
                                                const int* __restrict__ cnt, float* __restrict__ dinv, int n) {
    int i = blockIdx.x * blockDim.x + threadIdx.x;
    if (i < n) {
        off[i] += bsum[i >> 10];
        dinv[i] = rsqrtf((float)(cnt[i] + 1));  // deg includes self-loop, always >= 1
    }
}

__global__ __launch_bounds__(NBLK) void fill_k(const int* __restrict__ src, const int* __restrict__ dst, int E,
                                               const int* __restrict__ off, int* __restrict__ cursor,
                                               const float* __restrict__ dinv,
                                               int* __restrict__ srcs, float* __restrict__ norms) {
    int e = blockIdx.x * blockDim.x + threadIdx.x;
    if (e >= E) return;
    int s = src[e], d = dst[e];
    int pos = atomicAdd(&cursor[d], 1);
    int idx = off[d] + pos;
    srcs[idx] = s;
    norms[idx] = dinv[s] * dinv[d];
}

// ---------- dense: H = X @ W  (N x 128) @ (128 x 128), f32 ----------
// block = 256 (4 waves); block tile = 32 rows; wave handles 8 rows, lane handles 2 cols.
// LDS: W staged in two 64x128 halves (32KB) + X tile (16KB) = 48KB.

__global__ __launch_bounds__(NBLK) void gemm128_k(const float* __restrict__ X, const float* __restrict__ W,
                                                  float* __restrict__ H, int nrows) {
    __shared__ float Wl[64 * 128];
    __shared__ float Xl[32 * 128];
    int row0 = blockIdx.x * 32;

    // stage X tile (32 rows x 128 cols) as float4
    {
        const float4* Xv = (const float4*)X;
        float4* Xlv = (float4*)Xl;
        for (int i = threadIdx.x; i < 32 * 32; i += NBLK) {
            int r = row0 + (i >> 5);
            Xlv[i] = (r < nrows) ? Xv[(size_t)r * 32 + (i & 31)] : make_float4(0.f, 0.f, 0.f, 0.f);
        }
    }

    int wave = threadIdx.x >> 6;
    int lane = threadIdx.x & 63;
    int c2 = lane * 2;
    int rbase = wave * 8;

    float2 acc[8];
#pragma unroll
    for (int r = 0; r < 8; ++r) acc[r] = make_float2(0.f, 0.f);

    const float4* Wv = (const float4*)W;
    float4* Wlv = (float4*)Wl;

    for (int half = 0; half < 2; ++half) {
        __syncthreads();   // X staged (iter 0) / previous half consumed (iter 1)
        for (int i = threadIdx.x; i < 64 * 32; i += NBLK)
            Wlv[i] = Wv[half * 2048 + i];
        __syncthreads();
        int kb = half * 64;
        for (int k = 0; k < 64; ++k) {
            float2 w2 = *(const float2*)&Wl[k * 128 + c2];
#pragma unroll
            for (int r = 0; r < 8; ++r) {
                float xv = Xl[(rbase + r) * 128 + kb + k];
                acc[r].x = fmaf(xv, w2.x, acc[r].x);
                acc[r].y = fmaf(xv, w2.y, acc[r].y);
            }
        }
    }

#pragma unroll
    for (int r = 0; r < 8; ++r) {
        int row = row0 + rbase + r;
        if (row < nrows) *(float2*)&H[(size_t)row * 128 + c2] = acc[r];
    }
}

// ---------- aggregate: out[n] = sum_{e: dst=n} h[src]*norm + h[n]*dinv^2 + b, opt tanh ----------
// one wave per node; lane holds 2 dims (float2).

__global__ __launch_bounds__(NBLK) void aggregate_k(const float* __restrict__ H,
                                                    const int* __restrict__ off, const int* __restrict__ cnt,
                                                    const int* __restrict__ srcs, const float* __restrict__ norms,
                                                    const float* __restrict__ dinv, const float* __restrict__ bias,
                                                    float* __restrict__ out, int n, int apply_tanh) {
    int wid = (blockIdx.x * blockDim.x + threadIdx.x) >> 6;
    if (wid >= n) return;
    int lane = threadIdx.x & 63;
    int c2 = lane * 2;

    float dv = dinv[wid];
    float w = dv * dv;
    float2 hv = *(const float2*)&H[(size_t)wid * 128 + c2];
    float2 acc = make_float2(hv.x * w, hv.y * w);

    int e0 = off[wid];
    int e1 = e0 + cnt[wid];
    for (int e = e0; e < e1; ++e) {
        int s = srcs[e];
        float nm = norms[e];
        float2 hs = *(const float2*)&H[(size_t)s * 128 + c2];
        acc.x = fmaf(hs.x, nm, acc.x);
        acc.y = fmaf(hs.y, nm, acc.y);
    }

    float2 bv = *(const float2*)&bias[c2];
    acc.x += bv.x;
    acc.y += bv.y;
    if (apply_tanh) { acc.x = tanhf(acc.x); acc.y = tanhf(acc.y); }
    *(float2*)&out[(size_t)wid * 128 + c2] = acc;
}

// ---------- launch ----------

extern "C" void kernel_launch(void* const* d_in, const int* in_sizes, int n_in,
                              void* d_out, int out_size, void* d_ws, size_t ws_size,
                              hipStream_t stream) {
    const float* x  = (const float*)d_in[0];
    const float* W1 = (const float*)d_in[1];
    const float* b1 = (const float*)d_in[2];
    const float* W2 = (const float*)d_in[3];
    const float* b2 = (const float*)d_in[4];
    const int*   ei = (const int*)d_in[5];

    const int N = in_sizes[0] / 128;
    const int E = in_sizes[5] / 2;
    const int* src = ei;
    const int* dst = ei + E;

    char* p = (char*)d_ws;
    float* h     = (float*)p; p += (size_t)N * 128 * sizeof(float);
    int*   cnt   = (int*)p;   p += (size_t)N * sizeof(int);
    int*   off   = (int*)p;   p += (size_t)N * sizeof(int);
    int*   cursor= (int*)p;   p += (size_t)N * sizeof(int);
    float* dinv  = (float*)p; p += (size_t)N * sizeof(float);
    int*   srcs  = (int*)p;   p += (size_t)E * sizeof(int);
    float* norms = (float*)p; p += (size_t)E * sizeof(float);
    int*   bsum  = (int*)p;   p += 1024;

    float* t   = (float*)d_out;   // layer-1 activation lives in d_out (never read by aggregate pass 2)
    float* out = (float*)d_out;

    const int nb = (N + 1023) / 1024;

    init_k <<<(N + NBLK - 1) / NBLK, NBLK, 0, stream>>>(cnt, cursor, N);
    count_k<<<(E + NBLK - 1) / NBLK, NBLK, 0, stream>>>(dst, E, cnt);
    scan1_k<<<nb, NBLK, 0, stream>>>(cnt, N, off, bsum);
    scan2_k<<<1, 128, 0, stream>>>(bsum, nb);
    scan3_k<<<(N + NBLK - 1) / NBLK, NBLK, 0, stream>>>(off, bsum, cnt, dinv, N);
    fill_k <<<(E + NBLK - 1) / NBLK, NBLK, 0, stream>>>(src, dst, E, off, cursor, dinv, srcs, norms);

    const int gemm_blocks = (N + 31) / 32;
    const int agg_blocks  = (N + 3) / 4;   // 4 waves/block, 1 wave/node

    // layer 1
    gemm128_k  <<<gemm_blocks, NBLK, 0, stream>>>(x, W1, h, N);
    aggregate_k<<<agg_blocks, NBLK, 0, stream>>>(h, off, cnt, srcs, norms, dinv, b1, t, N, 1);
    // layer 2
    gemm128_k  <<<gemm_blocks, NBLK, 0, stream>>>(t, W2, h, N);
    aggregate_k<<<agg_blocks, NBLK, 0, stream>>>(h, off, cnt, srcs, norms, dinv, b2, out, N, 0);
}

// Round 2
// 300.038 us; speedup vs baseline: 1.1839x; 1.1839x over previous
//
#include <hip/hip_runtime.h>
#include <math.h>

#define NBLK 256

#define FMA4(s, v, a) { (a).x = fmaf((s), (v).x, (a).x); (a).y = fmaf((s), (v).y, (a).y); \
                        (a).z = fmaf((s), (v).z, (a).z); (a).w = fmaf((s), (v).w, (a).w); }

// ---------- preprocessing: CSR by dst ----------

__global__ __launch_bounds__(NBLK) void zero_k(int* p, int n) {
    int i = blockIdx.x * blockDim.x + threadIdx.x;
    if (i < n) p[i] = 0;
}

__global__ __launch_bounds__(NBLK) void count_k(const int* __restrict__ dst, int E, int* __restrict__ cnt) {
    int e = blockIdx.x * blockDim.x + threadIdx.x;
    if (e < E) atomicAdd(&cnt[dst[e]], 1);
}

// chunk = 1024 elems per block (256 threads x 4)
__global__ __launch_bounds__(NBLK) void scan1_k(const int* __restrict__ cnt, int n,
                                                int* __restrict__ off, int* __restrict__ bsum) {
    __shared__ int ls[NBLK];
    int base = blockIdx.x * 1024 + threadIdx.x * 4;
    int v[4]; int s = 0;
#pragma unroll
    for (int i = 0; i < 4; ++i) {
        int idx = base + i;
        v[i] = (idx < n) ? cnt[idx] : 0;
        s += v[i];
    }
    ls[threadIdx.x] = s;
    __syncthreads();
    for (int o = 1; o < NBLK; o <<= 1) {
        int t = (threadIdx.x >= (unsigned)o) ? ls[threadIdx.x - o] : 0;
        __syncthreads();
        ls[threadIdx.x] += t;
        __syncthreads();
    }
    int run = ls[threadIdx.x] - s;   // exclusive prefix within block
#pragma unroll
    for (int i = 0; i < 4; ++i) {
        int idx = base + i;
        if (idx < n) off[idx] = run;
        run += v[i];
    }
    if (threadIdx.x == NBLK - 1) bsum[blockIdx.x] = ls[NBLK - 1];
}

__global__ void scan2_k(int* bsum, int nb) {
    __shared__ int ls[128];
    int t = threadIdx.x;
    int v = (t < nb) ? bsum[t] : 0;
    ls[t] = v;
    __syncthreads();
    for (int o = 1; o < 128; o <<= 1) {
        int tv = (t >= o) ? ls[t - o] : 0;
        __syncthreads();
        ls[t] += tv;
        __syncthreads();
    }
    if (t < nb) bsum[t] = ls[t] - v;  // exclusive
}

__global__ __launch_bounds__(NBLK) void scan3_k(int* __restrict__ off, const int* __restrict__ bsum,
                                                const int* __restrict__ cnt, float* __restrict__ dinv, int n) {
    int i = blockIdx.x * blockDim.x + threadIdx.x;
    if (i < n) {
        off[i] += bsum[i >> 10];
        dinv[i] = rsqrtf((float)(cnt[i] + 1));  // deg includes self-loop
    }
}

__global__ __launch_bounds__(NBLK) void fill_k(const int* __restrict__ src, const int* __restrict__ dst, int E,
                                               const int* __restrict__ off, int* __restrict__ cursor,
                                               const float* __restrict__ dinv,
                                               int* __restrict__ srcs, float* __restrict__ norms) {
    int e = blockIdx.x * blockDim.x + threadIdx.x;
    if (e >= E) return;
    int s = src[e], d = dst[e];
    int pos = atomicAdd(&cursor[d], 1);
    int idx = off[d] + pos;
    srcs[idx] = s;
    norms[idx] = dinv[s] * dinv[d];
}

// ---------- dense: H = X @ W, f32, compute-bound layout ----------
// block 256, tile 64 rows x 128 cols. thread = 4 rows x 8 cols (two float4 col groups).
// W streamed in 4 chunks of 32 k-rows (16KB); X tile staged once (stride 132 -> 2-way max).

__global__ __launch_bounds__(NBLK) void gemm128_k(const float* __restrict__ X, const float* __restrict__ W,
                                                  float* __restrict__ H, int nrows) {
    __shared__ float Xl[64 * 132];
    __shared__ float Wl[32 * 128];
    const int row0 = blockIdx.x * 64;
    const int t = threadIdx.x;
    const int rg = t >> 4;   // 0..15 -> rows rg*4..rg*4+3
    const int cg = t & 15;   // 0..15 -> cols cg*4..+3 and 64+cg*4..+3

    // stage X tile (64 rows x 32 float4)
    {
        const float4* Xv = (const float4*)X;
        for (int i = t; i < 64 * 32; i += NBLK) {
            int r = i >> 5, c = i & 31;
            float4 v = make_float4(0.f, 0.f, 0.f, 0.f);
            if (row0 + r < nrows) v = Xv[(size_t)(row0 + r) * 32 + c];
            *(float4*)&Xl[r * 132 + c * 4] = v;
        }
    }

    float4 a0[4], a1[4];
#pragma unroll
    for (int i = 0; i < 4; ++i) { a0[i] = make_float4(0.f,0.f,0.f,0.f); a1[i] = make_float4(0.f,0.f,0.f,0.f); }

    const float4* Wv = (const float4*)W;
    for (int kc = 0; kc < 4; ++kc) {
        __syncthreads();           // X staged (kc=0) / prev W chunk consumed
        for (int i = t; i < 32 * 32; i += NBLK) {
            int r = i >> 5, c = i & 31;
            *(float4*)&Wl[r * 128 + c * 4] = Wv[(size_t)(kc * 32 + r) * 32 + c];
        }
        __syncthreads();
        for (int k4 = 0; k4 < 32; k4 += 4) {
            float4 xv[4];
#pragma unroll
            for (int i = 0; i < 4; ++i)
                xv[i] = *(const float4*)&Xl[(rg * 4 + i) * 132 + kc * 32 + k4];
#pragma unroll
            for (int kk = 0; kk < 4; ++kk) {
                float4 w0 = *(const float4*)&Wl[(k4 + kk) * 128 + cg * 4];
                float4 w1 = *(const float4*)&Wl[(k4 + kk) * 128 + 64 + cg * 4];
#pragma unroll
                for (int i = 0; i < 4; ++i) {
                    float xs = (&xv[i].x)[kk];
                    FMA4(xs, w0, a0[i]);
                    FMA4(xs, w1, a1[i]);
                }
            }
        }
    }

#pragma unroll
    for (int i = 0; i < 4; ++i) {
        int row = row0 + rg * 4 + i;
        if (row < nrows) {
            *(float4*)&H[(size_t)row * 128 + cg * 4] = a0[i];
            *(float4*)&H[(size_t)row * 128 + 64 + cg * 4] = a1[i];
        }
    }
}

// ---------- aggregate: out[n] = sum_{e: dst=n} h[src]*norm + h[n]*dinv^2 + b, opt tanh ----------
// one wave per node; 4 edge-slots x 16 lanes; lane covers dims [4sl..4sl+3] and [64+4sl..+3].
// unroll x2 -> 8 edges (16 b128 gathers) in flight per wave.

__global__ __launch_bounds__(NBLK) void aggregate_k(const float* __restrict__ H,
                                                    const int* __restrict__ off, const int* __restrict__ cnt,
                                                    const int* __restrict__ srcs, const float* __restrict__ norms,
                                                    const float* __restrict__ dinv, const float* __restrict__ bias,
                                                    float* __restrict__ out, int n, int apply_tanh) {
    int wid = (blockIdx.x * blockDim.x + threadIdx.x) >> 6;
    if (wid >= n) return;
    int lane = threadIdx.x & 63;
    int slot = lane >> 4;      // 0..3
    int sl   = lane & 15;      // 0..15

    const float4* Hv = (const float4*)H;
    size_t rbase = (size_t)wid * 32;

    float dv = dinv[wid];
    float w4 = dv * dv * 0.25f;          // each slot adds w/4 * h[self]; x4 on reduce = w exactly
    float4 h0 = Hv[rbase + sl];
    float4 h1 = Hv[rbase + 16 + sl];
    float4 acc0 = make_float4(h0.x * w4, h0.y * w4, h0.z * w4, h0.w * w4);
    float4 acc1 = make_float4(h1.x * w4, h1.y * w4, h1.z * w4, h1.w * w4);

    int e0 = off[wid];
    int e1 = e0 + cnt[wid];
    for (int b = e0; b < e1; b += 8) {
        int ea = b + slot;
        int eb = ea + 4;
        bool va = ea < e1, vb = eb < e1;
        int ca = va ? ea : (e1 - 1);     // loop entered => e1-1 >= e0 >= 0
        int cb = vb ? eb : (e1 - 1);
        int   sa = srcs[ca],  sb = srcs[cb];
        float na = va ? norms[ca] : 0.f;
        float nb = vb ? norms[cb] : 0.f;
        size_t ra = (size_t)sa * 32, rb = (size_t)sb * 32;
        float4 A0 = Hv[ra + sl], A1 = Hv[ra + 16 + sl];
        float4 B0 = Hv[rb + sl], B1 = Hv[rb + 16 + sl];
        FMA4(na, A0, acc0); FMA4(na, A1, acc1);
        FMA4(nb, B0, acc0); FMA4(nb, B1, acc1);
    }

    // reduce across 4 slots (lane bits 4,5)
#pragma unroll
    for (int m = 16; m <= 32; m <<= 1) {
        acc0.x += __shfl_xor(acc0.x, m, 64); acc0.y += __shfl_xor(acc0.y, m, 64);
        acc0.z += __shfl_xor(acc0.z, m, 64); acc0.w += __shfl_xor(acc0.w, m, 64);
        acc1.x += __shfl_xor(acc1.x, m, 64); acc1.y += __shfl_xor(acc1.y, m, 64);
        acc1.z += __shfl_xor(acc1.z, m, 64); acc1.w += __shfl_xor(acc1.w, m, 64);
    }

    if (slot == 0) {
        float4 bv0 = *(const float4*)&bias[sl * 4];
        float4 bv1 = *(const float4*)&bias[64 + sl * 4];
        acc0.x += bv0.x; acc0.y += bv0.y; acc0.z += bv0.z; acc0.w += bv0.w;
        acc1.x += bv1.x; acc1.y += bv1.y; acc1.z += bv1.z; acc1.w += bv1.w;
        if (apply_tanh) {
            acc0.x = tanhf(acc0.x); acc0.y = tanhf(acc0.y); acc0.z = tanhf(acc0.z); acc0.w = tanhf(acc0.w);
            acc1.x = tanhf(acc1.x); acc1.y = tanhf(acc1.y); acc1.z = tanhf(acc1.z); acc1.w = tanhf(acc1.w);
        }
        *(float4*)&out[(size_t)wid * 128 + sl * 4] = acc0;
        *(float4*)&out[(size_t)wid * 128 + 64 + sl * 4] = acc1;
    }
}

// ---------- launch ----------

extern "C" void kernel_launch(void* const* d_in, const int* in_sizes, int n_in,
                              void* d_out, int out_size, void* d_ws, size_t ws_size,
                              hipStream_t stream) {
    const float* x  = (const float*)d_in[0];
    const float* W1 = (const float*)d_in[1];
    const float* b1 = (const float*)d_in[2];
    const float* W2 = (const float*)d_in[3];
    const float* b2 = (const float*)d_in[4];
    const int*   ei = (const int*)d_in[5];

    const int N = in_sizes[0] / 128;
    const int E = in_sizes[5] / 2;
    const int* src = ei;
    const int* dst = ei + E;

    char* p = (char*)d_ws;
    float* h     = (float*)p; p += (size_t)N * 128 * sizeof(float);
    int*   cnt   = (int*)p;   p += (size_t)N * sizeof(int);
    int*   cursor= (int*)p;   p += (size_t)N * sizeof(int);   // contiguous with cnt for zero_k
    int*   off   = (int*)p;   p += (size_t)N * sizeof(int);
    float* dinv  = (float*)p; p += (size_t)N * sizeof(float);
    int*   srcs  = (int*)p;   p += (size_t)E * sizeof(int);
    float* norms = (float*)p; p += (size_t)E * sizeof(float);
    int*   bsum  = (int*)p;   p += 1024;

    float* t   = (float*)d_out;   // layer-1 activation lives in d_out (never read by pass-2 aggregate)
    float* out = (float*)d_out;

    const int nb = (N + 1023) / 1024;

    zero_k <<<(2 * N + NBLK - 1) / NBLK, NBLK, 0, stream>>>(cnt, 2 * N);
    count_k<<<(E + NBLK - 1) / NBLK, NBLK, 0, stream>>>(dst, E, cnt);
    scan1_k<<<nb, NBLK, 0, stream>>>(cnt, N, off, bsum);
    scan2_k<<<1, 128, 0, stream>>>(bsum, nb);
    scan3_k<<<(N + NBLK - 1) / NBLK, NBLK, 0, stream>>>(off, bsum, cnt, dinv, N);
    fill_k <<<(E + NBLK - 1) / NBLK, NBLK, 0, stream>>>(src, dst, E, off, cursor, dinv, srcs, norms);

    const int gemm_blocks = (N + 63) / 64;
    const int agg_blocks  = (N + 3) / 4;   // 4 waves/block, 1 wave/node

    gemm128_k  <<<gemm_blocks, NBLK, 0, stream>>>(x, W1, h, N);
    aggregate_k<<<agg_blocks, NBLK, 0, stream>>>(h, off, cnt, srcs, norms, dinv, b1, t, N, 1);
    gemm128_k  <<<gemm_blocks, NBLK, 0, stream>>>(t, W2, h, N);
    aggregate_k<<<agg_blocks, NBLK, 0, stream>>>(h, off, cnt, srcs, norms, dinv, b2, out, N, 0);
}

// Round 3
// 290.081 us; speedup vs baseline: 1.2245x; 1.0343x over previous
//
#include <hip/hip_runtime.h>
#include <math.h>

#define NBLK 256

#define FMA4(s, v, a) { (a).x = fmaf((s), (v).x, (a).x); (a).y = fmaf((s), (v).y, (a).y); \
                        (a).z = fmaf((s), (v).z, (a).z); (a).w = fmaf((s), (v).w, (a).w); }

__device__ __forceinline__ float fast_tanh(float x) {
    float cx = fminf(fmaxf(x, -15.f), 15.f);
    float e = __expf(2.f * cx);
    return (e - 1.f) / (e + 1.f);
}

// ---------- preprocessing: CSR by dst ----------

__global__ __launch_bounds__(NBLK) void zero_k(int* p, int n) {
    int i = blockIdx.x * blockDim.x + threadIdx.x;
    if (i < n) p[i] = 0;
}

__global__ __launch_bounds__(NBLK) void count_k(const int* __restrict__ dst, int E, int* __restrict__ cnt) {
    int e = blockIdx.x * blockDim.x + threadIdx.x;
    if (e < E) atomicAdd(&cnt[dst[e]], 1);
}

// chunk = 1024 elems per block (256 threads x 4)
__global__ __launch_bounds__(NBLK) void scan1_k(const int* __restrict__ cnt, int n,
                                                int* __restrict__ off, int* __restrict__ bsum) {
    __shared__ int ls[NBLK];
    int base = blockIdx.x * 1024 + threadIdx.x * 4;
    int v[4]; int s = 0;
#pragma unroll
    for (int i = 0; i < 4; ++i) {
        int idx = base + i;
        v[i] = (idx < n) ? cnt[idx] : 0;
        s += v[i];
    }
    ls[threadIdx.x] = s;
    __syncthreads();
    for (int o = 1; o < NBLK; o <<= 1) {
        int t = (threadIdx.x >= (unsigned)o) ? ls[threadIdx.x - o] : 0;
        __syncthreads();
        ls[threadIdx.x] += t;
        __syncthreads();
    }
    int run = ls[threadIdx.x] - s;   // exclusive prefix within block
#pragma unroll
    for (int i = 0; i < 4; ++i) {
        int idx = base + i;
        if (idx < n) off[idx] = run;
        run += v[i];
    }
    if (threadIdx.x == NBLK - 1) bsum[blockIdx.x] = ls[NBLK - 1];
}

__global__ void scan2_k(int* bsum, int nb) {
    __shared__ int ls[128];
    int t = threadIdx.x;
    int v = (t < nb) ? bsum[t] : 0;
    ls[t] = v;
    __syncthreads();
    for (int o = 1; o < 128; o <<= 1) {
        int tv = (t >= o) ? ls[t - o] : 0;
        __syncthreads();
        ls[t] += tv;
        __syncthreads();
    }
    if (t < nb) bsum[t] = ls[t] - v;  // exclusive
}

__global__ __launch_bounds__(NBLK) void scan3_k(int* __restrict__ off, const int* __restrict__ bsum,
                                                const int* __restrict__ cnt, float* __restrict__ dinv, int n) {
    int i = blockIdx.x * blockDim.x + threadIdx.x;
    if (i < n) {
        off[i] += bsum[i >> 10];
        dinv[i] = rsqrtf((float)(cnt[i] + 1));  // deg includes self-loop
    }
}

__global__ __launch_bounds__(NBLK) void fill_k(const int* __restrict__ src, const int* __restrict__ dst, int E,
                                               const int* __restrict__ off, int* __restrict__ cursor,
                                               const float* __restrict__ dinv,
                                               int* __restrict__ srcs, float* __restrict__ norms) {
    int e = blockIdx.x * blockDim.x + threadIdx.x;
    if (e >= E) return;
    int s = src[e], d = dst[e];
    int pos = atomicAdd(&cursor[d], 1);
    int idx = off[d] + pos;
    srcs[idx] = s;
    norms[idx] = dinv[s] * dinv[d];
}

// ---------- dense: H = X @ W, f32 ----------
// block 256 (4 waves), tile 64 rows x 128 cols; thread = 4 rows x 8 cols.
// BOTH X and W staged in 32-k chunks: LDS = 64x36f (9.2KB) + 32x128f (16KB) = 25.2KB -> 6 blocks/CU.

__global__ __launch_bounds__(NBLK) void gemm128_k(const float* __restrict__ X, const float* __restrict__ W,
                                                  float* __restrict__ H, int nrows) {
    __shared__ float Xl[64 * 36];
    __shared__ float Wl[32 * 128];
    const int row0 = blockIdx.x * 64;
    const int t = threadIdx.x;
    const int rg = t >> 4;   // 0..15 -> rows rg*4..rg*4+3
    const int cg = t & 15;   // 0..15 -> cols cg*4..+3 and 64+cg*4..+3

    float4 a0[4], a1[4];
#pragma unroll
    for (int i = 0; i < 4; ++i) { a0[i] = make_float4(0.f,0.f,0.f,0.f); a1[i] = make_float4(0.f,0.f,0.f,0.f); }

    const float4* Xv = (const float4*)X;
    const float4* Wv = (const float4*)W;

    for (int kc = 0; kc < 4; ++kc) {
        __syncthreads();   // previous chunk consumed
        // stage X chunk: 64 rows x 8 float4
        for (int i = t; i < 64 * 8; i += NBLK) {
            int r = i >> 3, c = i & 7;
            float4 v = make_float4(0.f, 0.f, 0.f, 0.f);
            if (row0 + r < nrows) v = Xv[(size_t)(row0 + r) * 32 + kc * 8 + c];
            *(float4*)&Xl[r * 36 + c * 4] = v;
        }
        // stage W chunk: 32 k-rows x 32 float4
        for (int i = t; i < 32 * 32; i += NBLK) {
            int r = i >> 5, c = i & 31;
            *(float4*)&Wl[r * 128 + c * 4] = Wv[(size_t)(kc * 32 + r) * 32 + c];
        }
        __syncthreads();
        for (int k4 = 0; k4 < 32; k4 += 4) {
            float4 xv[4];
#pragma unroll
            for (int i = 0; i < 4; ++i)
                xv[i] = *(const float4*)&Xl[(rg * 4 + i) * 36 + k4];
#pragma unroll
            for (int kk = 0; kk < 4; ++kk) {
                float4 w0 = *(const float4*)&Wl[(k4 + kk) * 128 + cg * 4];
                float4 w1 = *(const float4*)&Wl[(k4 + kk) * 128 + 64 + cg * 4];
#pragma unroll
                for (int i = 0; i < 4; ++i) {
                    float xs = (&xv[i].x)[kk];
                    FMA4(xs, w0, a0[i]);
                    FMA4(xs, w1, a1[i]);
                }
            }
        }
    }

#pragma unroll
    for (int i = 0; i < 4; ++i) {
        int row = row0 + rg * 4 + i;
        if (row < nrows) {
            *(float4*)&H[(size_t)row * 128 + cg * 4] = a0[i];
            *(float4*)&H[(size_t)row * 128 + 64 + cg * 4] = a1[i];
        }
    }
}

// ---------- aggregate ----------
// out[n] = sum_{e: dst=n} h[src]*norm + h[n]*dinv^2 + b, opt tanh.
// 8 nodes per wave, 8 lanes per node; lane il owns float4 slots {il, il+8, il+16, il+24}
// (each load instruction = one coalesced 128B segment per group). No cross-lane reduce.
// Edge loop per group is serial but unrolled x2 (8 b128 gathers in flight per lane).

__global__ __launch_bounds__(NBLK) void aggregate_k(const float* __restrict__ H,
                                                    const int* __restrict__ off, const int* __restrict__ cnt,
                                                    const int* __restrict__ srcs, const float* __restrict__ norms,
                                                    const float* __restrict__ dinv, const float* __restrict__ bias,
                                                    float* __restrict__ out, int n, int apply_tanh) {
    int node = (blockIdx.x * blockDim.x + threadIdx.x) >> 3;
    if (node >= n) return;
    int il = threadIdx.x & 7;

    const float4* Hv = (const float4*)H;
    size_t rbase = (size_t)node * 32;

    float dv = dinv[node];
    float w = dv * dv;
    float4 acc[4];
#pragma unroll
    for (int j = 0; j < 4; ++j) {
        float4 hv = Hv[rbase + il + 8 * j];
        acc[j] = make_float4(hv.x * w, hv.y * w, hv.z * w, hv.w * w);
    }

    int e0 = off[node];
    int deg = cnt[node];
    int it = 0;
    for (; it + 2 <= deg; it += 2) {
        int ea = e0 + it, eb = ea + 1;
        int sa = srcs[ea], sb = srcs[eb];
        float na = norms[ea], nb = norms[eb];
        size_t ra = (size_t)sa * 32, rb = (size_t)sb * 32;
        float4 A[4], B[4];
#pragma unroll
        for (int j = 0; j < 4; ++j) { A[j] = Hv[ra + il + 8 * j]; B[j] = Hv[rb + il + 8 * j]; }
#pragma unroll
        for (int j = 0; j < 4; ++j) { FMA4(na, A[j], acc[j]); FMA4(nb, B[j], acc[j]); }
    }
    if (it < deg) {
        int e = e0 + it;
        int s = srcs[e];
        float nm = norms[e];
        size_t rb = (size_t)s * 32;
#pragma unroll
        for (int j = 0; j < 4; ++j) {
            float4 hv = Hv[rb + il + 8 * j];
            FMA4(nm, hv, acc[j]);
        }
    }

#pragma unroll
    for (int j = 0; j < 4; ++j) {
        float4 bv = *(const float4*)&bias[(il + 8 * j) * 4];
        acc[j].x += bv.x; acc[j].y += bv.y; acc[j].z += bv.z; acc[j].w += bv.w;
    }
    if (apply_tanh) {
#pragma unroll
        for (int j = 0; j < 4; ++j) {
            acc[j].x = fast_tanh(acc[j].x); acc[j].y = fast_tanh(acc[j].y);
            acc[j].z = fast_tanh(acc[j].z); acc[j].w = fast_tanh(acc[j].w);
        }
    }
#pragma unroll
    for (int j = 0; j < 4; ++j)
        *(float4*)&out[(size_t)node * 128 + (il + 8 * j) * 4] = acc[j];
}

// ---------- launch ----------

extern "C" void kernel_launch(void* const* d_in, const int* in_sizes, int n_in,
                              void* d_out, int out_size, void* d_ws, size_t ws_size,
                              hipStream_t stream) {
    const float* x  = (const float*)d_in[0];
    const float* W1 = (const float*)d_in[1];
    const float* b1 = (const float*)d_in[2];
    const float* W2 = (const float*)d_in[3];
    const float* b2 = (const float*)d_in[4];
    const int*   ei = (const int*)d_in[5];

    const int N = in_sizes[0] / 128;
    const int E = in_sizes[5] / 2;
    const int* src = ei;
    const int* dst = ei + E;

    char* p = (char*)d_ws;
    float* h     = (float*)p; p += (size_t)N * 128 * sizeof(float);
    int*   cnt   = (int*)p;   p += (size_t)N * sizeof(int);
    int*   cursor= (int*)p;   p += (size_t)N * sizeof(int);   // contiguous with cnt for zero_k
    int*   off   = (int*)p;   p += (size_t)N * sizeof(int);
    float* dinv  = (float*)p; p += (size_t)N * sizeof(float);
    int*   srcs  = (int*)p;   p += (size_t)E * sizeof(int);
    float* norms = (float*)p; p += (size_t)E * sizeof(float);
    int*   bsum  = (int*)p;   p += 1024;

    float* t   = (float*)d_out;   // layer-1 activation lives in d_out (never read by pass-2 aggregate)
    float* out = (float*)d_out;

    const int nb = (N + 1023) / 1024;

    zero_k <<<(2 * N + NBLK - 1) / NBLK, NBLK, 0, stream>>>(cnt, 2 * N);
    count_k<<<(E + NBLK - 1) / NBLK, NBLK, 0, stream>>>(dst, E, cnt);
    scan1_k<<<nb, NBLK, 0, stream>>>(cnt, N, off, bsum);
    scan2_k<<<1, 128, 0, stream>>>(bsum, nb);
    scan3_k<<<(N + NBLK - 1) / NBLK, NBLK, 0, stream>>>(off, bsum, cnt, dinv, N);
    fill_k <<<(E + NBLK - 1) / NBLK, NBLK, 0, stream>>>(src, dst, E, off, cursor, dinv, srcs, norms);

    const int gemm_blocks = (N + 63) / 64;
    const int agg_blocks  = (N + 31) / 32;   // 32 nodes per block (8 per wave)

    gemm128_k  <<<gemm_blocks, NBLK, 0, stream>>>(x, W1, h, N);
    aggregate_k<<<agg_blocks, NBLK, 0, stream>>>(h, off, cnt, srcs, norms, dinv, b1, t, N, 1);
    gemm128_k  <<<gemm_blocks, NBLK, 0, stream>>>(t, W2, h, N);
    aggregate_k<<<agg_blocks, NBLK, 0, stream>>>(h, off, cnt, srcs, norms, dinv, b2, out, N, 0);
}

// Round 4
// 183.824 us; speedup vs baseline: 1.9323x; 1.5780x over previous
//
#include <hip/hip_runtime.h>
#include <math.h>

#define NBLK 256

typedef __attribute__((ext_vector_type(8))) short short8v;  // 8 bf16 (4 VGPR)
typedef __attribute__((ext_vector_type(4))) float f32x4;

__device__ __forceinline__ unsigned cvt_pk_bf16(float lo, float hi) {
    unsigned r;
    asm("v_cvt_pk_bf16_f32 %0, %1, %2" : "=v"(r) : "v"(lo), "v"(hi));
    return r;
}
__device__ __forceinline__ float bf_lo(unsigned u) { return __uint_as_float(u << 16); }
__device__ __forceinline__ float bf_hi(unsigned u) { return __uint_as_float(u & 0xffff0000u); }

__device__ __forceinline__ float fast_tanh(float x) {
    float cx = fminf(fmaxf(x, -15.f), 15.f);
    float e = __expf(2.f * cx);
    return (e - 1.f) / (e + 1.f);
}

// ---------- preprocessing: CSR by dst ----------

__global__ __launch_bounds__(NBLK) void zero_k(int* p, int n) {
    int i = blockIdx.x * blockDim.x + threadIdx.x;
    if (i < n) p[i] = 0;
}

__global__ __launch_bounds__(NBLK) void count_k(const int* __restrict__ dst, int E, int* __restrict__ cnt) {
    int e = blockIdx.x * blockDim.x + threadIdx.x;
    if (e < E) atomicAdd(&cnt[dst[e]], 1);
}

__global__ __launch_bounds__(NBLK) void scan1_k(const int* __restrict__ cnt, int n,
                                                int* __restrict__ off, int* __restrict__ bsum) {
    __shared__ int ls[NBLK];
    int base = blockIdx.x * 1024 + threadIdx.x * 4;
    int v[4]; int s = 0;
#pragma unroll
    for (int i = 0; i < 4; ++i) {
        int idx = base + i;
        v[i] = (idx < n) ? cnt[idx] : 0;
        s += v[i];
    }
    ls[threadIdx.x] = s;
    __syncthreads();
    for (int o = 1; o < NBLK; o <<= 1) {
        int t = (threadIdx.x >= (unsigned)o) ? ls[threadIdx.x - o] : 0;
        __syncthreads();
        ls[threadIdx.x] += t;
        __syncthreads();
    }
    int run = ls[threadIdx.x] - s;
#pragma unroll
    for (int i = 0; i < 4; ++i) {
        int idx = base + i;
        if (idx < n) off[idx] = run;
        run += v[i];
    }
    if (threadIdx.x == NBLK - 1) bsum[blockIdx.x] = ls[NBLK - 1];
}

__global__ void scan2_k(int* bsum, int nb) {
    __shared__ int ls[128];
    int t = threadIdx.x;
    int v = (t < nb) ? bsum[t] : 0;
    ls[t] = v;
    __syncthreads();
    for (int o = 1; o < 128; o <<= 1) {
        int tv = (t >= o) ? ls[t - o] : 0;
        __syncthreads();
        ls[t] += tv;
        __syncthreads();
    }
    if (t < nb) bsum[t] = ls[t] - v;
}

__global__ __launch_bounds__(NBLK) void scan3_k(int* __restrict__ off, const int* __restrict__ bsum,
                                                const int* __restrict__ cnt, float* __restrict__ dinv, int n) {
    int i = blockIdx.x * blockDim.x + threadIdx.x;
    if (i < n) {
        off[i] += bsum[i >> 10];
        dinv[i] = rsqrtf((float)(cnt[i] + 1));
    }
}

__global__ __launch_bounds__(NBLK) void fill_k(const int* __restrict__ src, const int* __restrict__ dst, int E,
                                               const int* __restrict__ off, int* __restrict__ cursor,
                                               const float* __restrict__ dinv,
                                               int* __restrict__ srcs, float* __restrict__ norms) {
    int e = blockIdx.x * blockDim.x + threadIdx.x;
    if (e >= E) return;
    int s = src[e], d = dst[e];
    int pos = atomicAdd(&cursor[d], 1);
    int idx = off[d] + pos;
    srcs[idx] = s;
    norms[idx] = dinv[s] * dinv[d];
}

// cast + transpose both weight matrices: Wt[col][k] bf16 (128x128 each)
__global__ __launch_bounds__(NBLK) void wcast_k(const float* __restrict__ W1, const float* __restrict__ W2,
                                                ushort* __restrict__ Wt1, ushort* __restrict__ Wt2) {
    int i = blockIdx.x * blockDim.x + threadIdx.x;   // 0..32767
    int which = i >> 14;
    int idx = i & 16383;
    const float* W = which ? W2 : W1;
    ushort* Wt = which ? Wt2 : Wt1;
    int k = idx >> 7, c = idx & 127;
    float v = W[idx];
    Wt[c * 128 + k] = (ushort)(cvt_pk_bf16(v, v) & 0xffffu);
}

// ---------- GEMM: Hb(bf16) = Xin @ W via MFMA 16x16x32 bf16 ----------
// block 256 = 4 waves; block tile 64 rows; wave tile 16 rows x 128 cols.
// B-frags (all of W) resident in registers (32 frags = 128 VGPR), loaded once per wave.
// X staged coalesced -> (cvt) -> XOR-swizzled LDS (conflict-free b128 write+read).
// A-frag layout: row = lane&15, k = (lane>>4)*8 + j. B: col = lane&15, k likewise.
// D: col = lane&15, row = (lane>>4)*4 + reg  [m89-verified].

template<int CVT>
__global__ __launch_bounds__(NBLK, 2) void gemm_mfma_k(const void* __restrict__ Xin,
                                                       const ushort* __restrict__ Wt,
                                                       ushort* __restrict__ Hb, int nrows, int nbt) {
    __shared__ unsigned Xls[64 * 64];   // 64 rows x 16 units(8 bf16) x 4 uint, swizzled; 16KB
    const int t = threadIdx.x;
    const int lane = t & 63;
    const int wv = t >> 6;
    const int l15 = lane & 15;
    const int g = lane >> 4;

    short8v B[4][8];
#pragma unroll
    for (int ks = 0; ks < 4; ++ks)
#pragma unroll
        for (int nt = 0; nt < 8; ++nt) {
            int col = nt * 16 + l15;
            int k0 = ks * 32 + g * 8;
            B[ks][nt] = *(const short8v*)&Wt[col * 128 + k0];
        }

    for (int bt = blockIdx.x; bt < nbt; bt += gridDim.x) {
        int row0 = bt * 64;
        __syncthreads();   // previous iteration's frag reads complete
        {
            int r = t >> 2;
            int rg = row0 + r;
#pragma unroll
            for (int j = 0; j < 4; ++j) {
                int u = (t & 3) + 4 * j;
                uint4 val;
                if (CVT) {
                    float4 f0 = make_float4(0.f,0.f,0.f,0.f), f1 = f0;
                    if (rg < nrows) {
                        const float4* Xv = (const float4*)Xin;
                        f0 = Xv[(size_t)rg * 32 + u * 2];
                        f1 = Xv[(size_t)rg * 32 + u * 2 + 1];
                    }
                    val.x = cvt_pk_bf16(f0.x, f0.y); val.y = cvt_pk_bf16(f0.z, f0.w);
                    val.z = cvt_pk_bf16(f1.x, f1.y); val.w = cvt_pk_bf16(f1.z, f1.w);
                } else {
                    val = make_uint4(0u,0u,0u,0u);
                    if (rg < nrows) val = ((const uint4*)Xin)[(size_t)rg * 16 + u];
                }
                *(uint4*)&Xls[r * 64 + ((u ^ (r & 15)) << 2)] = val;
            }
        }
        __syncthreads();

        short8v A[4];
#pragma unroll
        for (int ks = 0; ks < 4; ++ks) {
            int r = wv * 16 + l15;
            int u = ks * 4 + g;
            A[ks] = *(short8v*)&Xls[r * 64 + ((u ^ l15) << 2)];
        }

        f32x4 acc[8];
#pragma unroll
        for (int nt = 0; nt < 8; ++nt) acc[nt] = (f32x4){0.f, 0.f, 0.f, 0.f};
#pragma unroll
        for (int ks = 0; ks < 4; ++ks)
#pragma unroll
            for (int nt = 0; nt < 8; ++nt)
                acc[nt] = __builtin_amdgcn_mfma_f32_16x16x32_bf16(A[ks], B[ks][nt], acc[nt], 0, 0, 0);

        int trow0 = row0 + wv * 16;
#pragma unroll
        for (int nt = 0; nt < 8; ++nt)
#pragma unroll
            for (int q = 0; q < 4; ++q) {
                int row = trow0 + g * 4 + q;
                if (row < nrows)
                    Hb[(size_t)row * 128 + nt * 16 + l15] =
                        (ushort)(cvt_pk_bf16(acc[nt][q], acc[nt][q]) & 0xffffu);
            }
    }
}

// ---------- aggregate (bf16 gather) ----------
// 8 nodes/wave, 8 lanes/node; lane il owns uint4 units {il, il+8} = dims [il*8,+8) & [64+il*8,+8).
// unroll x4 -> 8 b128 gathers in flight per lane.

#define UPK_FMA(u4, nm, A) { \
    A[0] = fmaf(bf_lo((u4).x), (nm), A[0]); A[1] = fmaf(bf_hi((u4).x), (nm), A[1]); \
    A[2] = fmaf(bf_lo((u4).y), (nm), A[2]); A[3] = fmaf(bf_hi((u4).y), (nm), A[3]); \
    A[4] = fmaf(bf_lo((u4).z), (nm), A[4]); A[5] = fmaf(bf_hi((u4).z), (nm), A[5]); \
    A[6] = fmaf(bf_lo((u4).w), (nm), A[6]); A[7] = fmaf(bf_hi((u4).w), (nm), A[7]); }

template<int OUT_BF16>
__global__ __launch_bounds__(NBLK) void aggregate_k(const ushort* __restrict__ Hb,
                                                    const int* __restrict__ off, const int* __restrict__ cnt,
                                                    const int* __restrict__ srcs, const float* __restrict__ norms,
                                                    const float* __restrict__ dinv, const float* __restrict__ bias,
                                                    void* __restrict__ outp, int n, int apply_tanh) {
    int node = (blockIdx.x * blockDim.x + threadIdx.x) >> 3;
    if (node >= n) return;
    int il = threadIdx.x & 7;

    const uint4* Hv = (const uint4*)Hb;   // 16 uint4 per row
    float acc[16];
#pragma unroll
    for (int i = 0; i < 16; ++i) acc[i] = 0.f;

    float dv = dinv[node];
    float w = dv * dv;
    {
        size_t rb = (size_t)node * 16;
        uint4 s0 = Hv[rb + il], s1 = Hv[rb + 8 + il];
        UPK_FMA(s0, w, acc);
        UPK_FMA(s1, w, (acc + 8));
    }

    int e0 = off[node];
    int deg = cnt[node];
    int eLast = e0 + deg - 1;
    for (int b = 0; b < deg; b += 4) {
        int sidx[4]; float nm[4];
#pragma unroll
        for (int q = 0; q < 4; ++q) {
            bool v = (b + q) < deg;
            int ce = v ? (e0 + b + q) : eLast;
            sidx[q] = srcs[ce];
            nm[q] = v ? norms[ce] : 0.f;
        }
        uint4 g0[4], g1[4];
#pragma unroll
        for (int q = 0; q < 4; ++q) {
            size_t r = (size_t)sidx[q] * 16;
            g0[q] = Hv[r + il];
            g1[q] = Hv[r + 8 + il];
        }
#pragma unroll
        for (int q = 0; q < 4; ++q) {
            UPK_FMA(g0[q], nm[q], acc);
            UPK_FMA(g1[q], nm[q], (acc + 8));
        }
    }

    float4 b0 = *(const float4*)&bias[il * 8];
    float4 b1 = *(const float4*)&bias[il * 8 + 4];
    float4 b2 = *(const float4*)&bias[64 + il * 8];
    float4 b3 = *(const float4*)&bias[64 + il * 8 + 4];
    acc[0] += b0.x; acc[1] += b0.y; acc[2]  += b0.z; acc[3]  += b0.w;
    acc[4] += b1.x; acc[5] += b1.y; acc[6]  += b1.z; acc[7]  += b1.w;
    acc[8] += b2.x; acc[9] += b2.y; acc[10] += b2.z; acc[11] += b2.w;
    acc[12] += b3.x; acc[13] += b3.y; acc[14] += b3.z; acc[15] += b3.w;

    if (apply_tanh) {
#pragma unroll
        for (int i = 0; i < 16; ++i) acc[i] = fast_tanh(acc[i]);
    }

    if (OUT_BF16) {
        uint4 o0, o1;
        o0.x = cvt_pk_bf16(acc[0],  acc[1]);  o0.y = cvt_pk_bf16(acc[2],  acc[3]);
        o0.z = cvt_pk_bf16(acc[4],  acc[5]);  o0.w = cvt_pk_bf16(acc[6],  acc[7]);
        o1.x = cvt_pk_bf16(acc[8],  acc[9]);  o1.y = cvt_pk_bf16(acc[10], acc[11]);
        o1.z = cvt_pk_bf16(acc[12], acc[13]); o1.w = cvt_pk_bf16(acc[14], acc[15]);
        uint4* O = (uint4*)outp;
        O[(size_t)node * 16 + il] = o0;
        O[(size_t)node * 16 + 8 + il] = o1;
    } else {
        float* O = (float*)outp;
        *(float4*)&O[(size_t)node * 128 + il * 8]      = make_float4(acc[0], acc[1], acc[2], acc[3]);
        *(float4*)&O[(size_t)node * 128 + il * 8 + 4]  = make_float4(acc[4], acc[5], acc[6], acc[7]);
        *(float4*)&O[(size_t)node * 128 + 64 + il * 8]     = make_float4(acc[8], acc[9], acc[10], acc[11]);
        *(float4*)&O[(size_t)node * 128 + 64 + il * 8 + 4] = make_float4(acc[12], acc[13], acc[14], acc[15]);
    }
}

// ---------- launch ----------

extern "C" void kernel_launch(void* const* d_in, const int* in_sizes, int n_in,
                              void* d_out, int out_size, void* d_ws, size_t ws_size,
                              hipStream_t stream) {
    const float* x  = (const float*)d_in[0];
    const float* W1 = (const float*)d_in[1];
    const float* b1 = (const float*)d_in[2];
    const float* W2 = (const float*)d_in[3];
    const float* b2 = (const float*)d_in[4];
    const int*   ei = (const int*)d_in[5];

    const int N = in_sizes[0] / 128;
    const int E = in_sizes[5] / 2;
    const int* src = ei;
    const int* dst = ei + E;

    char* p = (char*)d_ws;
    ushort* hb    = (ushort*)p; p += (size_t)N * 128 * sizeof(ushort);   // bf16 h
    ushort* tb    = (ushort*)p; p += (size_t)N * 128 * sizeof(ushort);   // bf16 layer-1 activation
    int*    cnt   = (int*)p;    p += (size_t)N * sizeof(int);
    int*    cursor= (int*)p;    p += (size_t)N * sizeof(int);
    int*    off   = (int*)p;    p += (size_t)N * sizeof(int);
    float*  dinv  = (float*)p;  p += (size_t)N * sizeof(float);
    int*    srcs  = (int*)p;    p += (size_t)E * sizeof(int);
    float*  norms = (float*)p;  p += (size_t)E * sizeof(float);
    ushort* Wt1   = (ushort*)p; p += 16384 * sizeof(ushort);
    ushort* Wt2   = (ushort*)p; p += 16384 * sizeof(ushort);
    int*    bsum  = (int*)p;    p += 1024;

    const int nb = (N + 1023) / 1024;
    const int nbt = (N + 63) / 64;

    zero_k <<<(2 * N + NBLK - 1) / NBLK, NBLK, 0, stream>>>(cnt, 2 * N);
    count_k<<<(E + NBLK - 1) / NBLK, NBLK, 0, stream>>>(dst, E, cnt);
    scan1_k<<<nb, NBLK, 0, stream>>>(cnt, N, off, bsum);
    scan2_k<<<1, 128, 0, stream>>>(bsum, nb);
    scan3_k<<<(N + NBLK - 1) / NBLK, NBLK, 0, stream>>>(off, bsum, cnt, dinv, N);
    fill_k <<<(E + NBLK - 1) / NBLK, NBLK, 0, stream>>>(src, dst, E, off, cursor, dinv, srcs, norms);
    wcast_k<<<128, NBLK, 0, stream>>>(W1, W2, Wt1, Wt2);

    const int agg_blocks = (N * 8 + NBLK - 1) / NBLK;   // 8 lanes/node

    gemm_mfma_k<1><<<512, NBLK, 0, stream>>>(x, Wt1, hb, N, nbt);
    aggregate_k<1><<<agg_blocks, NBLK, 0, stream>>>(hb, off, cnt, srcs, norms, dinv, b1, tb, N, 1);
    gemm_mfma_k<0><<<512, NBLK, 0, stream>>>(tb, Wt2, hb, N, nbt);
    aggregate_k<0><<<agg_blocks, NBLK, 0, stream>>>(hb, off, cnt, srcs, norms, dinv, b2, d_out, N, 0);
}